// Round 1
// baseline (126.810 us; speedup 1.0000x reference)
//
#include <hip/hip_runtime.h>

// HEGN loss: L_reg + bidirectional chamfer(x, y).
// B=8, N=M=4096 (hardcoded from the reference).
#define BB 8
#define NN 4096
#define MC 512                   // reference points staged per chunk
#define NCHUNK (NN / MC)         // 8
#define KPT 4                    // query points per thread
#define TPB 256
#define PTS_PER_BLOCK (TPB * KPT) // 1024

// ws layout: float[0] = chamfer accumulator; float[64...] = partial mins
//            partial[c][zb][p]  c in [0,8), zb in [0,16), p in [0,4096)  -> 2 MB

__global__ __launch_bounds__(TPB) void chamfer_partial(
    const float* __restrict__ X, const float* __restrict__ Y,
    float* __restrict__ partial) {
  __shared__ float4 ly[MC];
  const int tid = threadIdx.x;
  const int zb  = blockIdx.z;        // 0..15 : (dir<<3) | b
  const int b   = zb & (BB - 1);
  const int dir = zb >> 3;
  const float* pts  = dir ? (Y + b * NN * 3) : (X + b * NN * 3);
  const float* refs = dir ? (X + b * NN * 3) : (Y + b * NN * 3);
  const int c = blockIdx.y;

  // Stage this chunk of reference points as (y0,y1,y2, |y|^2).
  for (int i = tid; i < MC; i += TPB) {
    const int j = c * MC + i;
    const float a0 = refs[j * 3 + 0];
    const float a1 = refs[j * 3 + 1];
    const float a2 = refs[j * 3 + 2];
    ly[i] = make_float4(a0, a1, a2, a0 * a0 + a1 * a1 + a2 * a2);
  }
  __syncthreads();

  float px[KPT], py[KPT], pz[KPT], m[KPT];
  const int p0 = blockIdx.x * PTS_PER_BLOCK + tid;
#pragma unroll
  for (int k = 0; k < KPT; k++) {
    const int p = p0 + k * TPB;
    px[k] = pts[p * 3 + 0];
    py[k] = pts[p * 3 + 1];
    pz[k] = pts[p * 3 + 2];
    m[k] = 1e30f;
  }

  // min over chunk of (|y|^2 - 2 x.y); |x|^2 added after the loop.
#pragma unroll 2
  for (int j = 0; j < MC; j++) {
    const float4 w = ly[j];
#pragma unroll
    for (int k = 0; k < KPT; k++) {
      const float xy = px[k] * w.x + py[k] * w.y + pz[k] * w.z;
      const float s  = fmaf(-2.0f, xy, w.w);
      m[k] = fminf(m[k], s);
    }
  }

#pragma unroll
  for (int k = 0; k < KPT; k++) {
    const int p = p0 + k * TPB;
    const float pn = px[k] * px[k] + py[k] * py[k] + pz[k] * pz[k];
    partial[(c * (2 * BB) + zb) * NN + p] = m[k] + pn;
  }
}

__global__ __launch_bounds__(256) void chamfer_reduce(
    const float* __restrict__ partial, float* __restrict__ acc) {
  const int g = blockIdx.x * 256 + threadIdx.x;  // over 2*BB*NN points
  float m = 1e30f;
#pragma unroll
  for (int c = 0; c < NCHUNK; c++)
    m = fminf(m, partial[c * (2 * BB * NN) + g]);
  // wave-64 shuffle sum
  for (int o = 32; o > 0; o >>= 1) m += __shfl_down(m, o);
  if ((threadIdx.x & 63) == 0) atomicAdd(acc, m);
}

__global__ __launch_bounds__(128) void finalize(
    const float* __restrict__ R, const float* __restrict__ S,
    const float* __restrict__ t, const float* __restrict__ Rgt,
    const float* __restrict__ Sgt, const float* __restrict__ tgt,
    const float* __restrict__ acc, float* __restrict__ out) {
  const int tid = threadIdx.x;
  float v = 0.0f;
  if (tid < 72) {                       // R @ R_gt^T - I, squared
    const int b = tid / 9, ik = tid % 9, i = ik / 3, k = ik % 3;
    const float* Rb = R + b * 9;
    const float* Gb = Rgt + b * 9;
    float s = Rb[i * 3 + 0] * Gb[k * 3 + 0] +
              Rb[i * 3 + 1] * Gb[k * 3 + 1] +
              Rb[i * 3 + 2] * Gb[k * 3 + 2];
    s -= (i == k) ? 1.0f : 0.0f;
    v = s * s;
  } else if (tid < 96) {                // (S - S_gt)^2, 24 elems
    const int i = tid - 72;
    const float s = S[i] - Sgt[i];
    v = s * s;
  } else if (tid < 120) {               // (t - t_gt)^2, 24 elems
    const int i = tid - 96;
    const float s = t[i] - tgt[i];
    v = s * s;
  }
  __shared__ float sm[128];
  sm[tid] = v;
  __syncthreads();
  for (int o = 64; o > 0; o >>= 1) {
    if (tid < o) sm[tid] += sm[tid + o];
    __syncthreads();
  }
  if (tid == 0) out[0] = sm[0] + acc[0] * (1.0f / (float)(BB * NN));
}

extern "C" void kernel_launch(void* const* d_in, const int* in_sizes, int n_in,
                              void* d_out, int out_size, void* d_ws, size_t ws_size,
                              hipStream_t stream) {
  const float* X   = (const float*)d_in[0];
  const float* Y   = (const float*)d_in[1];
  const float* R   = (const float*)d_in[2];
  const float* S   = (const float*)d_in[3];
  const float* t   = (const float*)d_in[4];
  const float* Rgt = (const float*)d_in[5];
  const float* Sgt = (const float*)d_in[6];
  const float* tgt = (const float*)d_in[7];

  float* acc     = (float*)d_ws;
  float* partial = ((float*)d_ws) + 64;

  hipMemsetAsync(acc, 0, sizeof(float), stream);

  dim3 gA(NN / PTS_PER_BLOCK, NCHUNK, 2 * BB);
  chamfer_partial<<<gA, TPB, 0, stream>>>(X, Y, partial);

  chamfer_reduce<<<(2 * BB * NN) / 256, 256, 0, stream>>>(partial, acc);

  finalize<<<1, 128, 0, stream>>>(R, S, t, Rgt, Sgt, tgt, acc, (float*)d_out);
}

// Round 2
// 97.624 us; speedup vs baseline: 1.2990x; 1.2990x over previous
//
#include <hip/hip_runtime.h>

// HEGN loss: L_reg + bidirectional chamfer(x, y).  B=8, N=M=4096.
#define BB 8
#define NN 4096
#define MC 256                    // reference points staged per chunk
#define NCHUNK (NN / MC)          // 16
#define KPT 8                     // query points per thread
#define TPB 256
#define PTS_PER_BLOCK (TPB * KPT) // 2048
#define NPTS (2 * BB * NN)        // 65536 (both directions)

// ws layout: partial[c][zb][p]  c in [0,16), zb in [0,16), p in [0,4096) -> 4 MB

__global__ __launch_bounds__(TPB) void chamfer_partial(
    const float* __restrict__ X, const float* __restrict__ Y,
    float* __restrict__ partial) {
  __shared__ float4 ly[MC];       // (-2*y0, -2*y1, -2*y2, |y|^2)
  const int tid = threadIdx.x;
  const int zb  = blockIdx.z;     // (dir<<3) | b
  const int b   = zb & (BB - 1);
  const int dir = zb >> 3;
  const float* pts  = dir ? (Y + b * NN * 3) : (X + b * NN * 3);
  const float* refs = dir ? (X + b * NN * 3) : (Y + b * NN * 3);
  const int c = blockIdx.y;

  {
    const int j = c * MC + tid;   // MC == TPB: one staging iteration
    const float a0 = refs[j * 3 + 0];
    const float a1 = refs[j * 3 + 1];
    const float a2 = refs[j * 3 + 2];
    ly[tid] = make_float4(-2.0f * a0, -2.0f * a1, -2.0f * a2,
                          a0 * a0 + a1 * a1 + a2 * a2);
  }
  __syncthreads();

  float px[KPT], py[KPT], pz[KPT], m[KPT];
  const int p0 = blockIdx.x * PTS_PER_BLOCK + tid;
#pragma unroll
  for (int k = 0; k < KPT; k++) {
    const int p = p0 + k * TPB;
    px[k] = pts[p * 3 + 0];
    py[k] = pts[p * 3 + 1];
    pz[k] = pts[p * 3 + 2];
    m[k] = 1e30f;
  }

  // min over chunk of (|y|^2 - 2 x.y); |x|^2 added after the loop.
#pragma unroll 2
  for (int j = 0; j < MC; j += 2) {
    const float4 w0 = ly[j];
    const float4 w1 = ly[j + 1];
#pragma unroll
    for (int k = 0; k < KPT; k++) {
      const float s0 = fmaf(px[k], w0.x, fmaf(py[k], w0.y, fmaf(pz[k], w0.z, w0.w)));
      const float s1 = fmaf(px[k], w1.x, fmaf(py[k], w1.y, fmaf(pz[k], w1.z, w1.w)));
      m[k] = fminf(m[k], fminf(s0, s1));   // -> v_min3_f32
    }
  }

#pragma unroll
  for (int k = 0; k < KPT; k++) {
    const int p = p0 + k * TPB;
    const float pn = px[k] * px[k] + py[k] * py[k] + pz[k] * pz[k];
    partial[(c * (2 * BB) + zb) * NN + p] = m[k] + pn;
  }
}

// Min across chunks, block-sum, 1 atomic per block into out (pre-zeroed).
// Block 0 also adds L_reg.
__global__ __launch_bounds__(256) void chamfer_reduce(
    const float* __restrict__ partial,
    const float* __restrict__ R, const float* __restrict__ S,
    const float* __restrict__ t, const float* __restrict__ Rgt,
    const float* __restrict__ Sgt, const float* __restrict__ tgt,
    float* __restrict__ out) {
  const int tid = threadIdx.x;
  const int q0 = blockIdx.x * 1024 + tid;   // 64 blocks cover NPTS
  float s = 0.0f;
#pragma unroll
  for (int kk = 0; kk < 4; kk++) {
    const int q = q0 + kk * 256;
    float m = 1e30f;
#pragma unroll
    for (int c = 0; c < NCHUNK; c++)
      m = fminf(m, partial[c * NPTS + q]);
    s += m;
  }
  for (int o = 32; o > 0; o >>= 1) s += __shfl_down(s, o);
  __shared__ float wsum[4];
  if ((tid & 63) == 0) wsum[tid >> 6] = s;
  __syncthreads();
  if (tid == 0) {
    const float bs = wsum[0] + wsum[1] + wsum[2] + wsum[3];
    atomicAdd(out, bs * (1.0f / (float)(BB * NN)));
  }

  if (blockIdx.x == 0) {
    float v = 0.0f;
    if (tid < 72) {                       // R @ R_gt^T - I, squared
      const int b = tid / 9, ik = tid % 9, i = ik / 3, k = ik % 3;
      const float* Rb = R + b * 9;
      const float* Gb = Rgt + b * 9;
      float d = Rb[i * 3 + 0] * Gb[k * 3 + 0] +
                Rb[i * 3 + 1] * Gb[k * 3 + 1] +
                Rb[i * 3 + 2] * Gb[k * 3 + 2];
      d -= (i == k) ? 1.0f : 0.0f;
      v = d * d;
    } else if (tid < 96) {                // (S - S_gt)^2
      const int i = tid - 72;
      const float d = S[i] - Sgt[i];
      v = d * d;
    } else if (tid < 120) {               // (t - t_gt)^2
      const int i = tid - 96;
      const float d = t[i] - tgt[i];
      v = d * d;
    }
    for (int o = 32; o > 0; o >>= 1) v += __shfl_down(v, o);
    __shared__ float rsum[4];
    if ((tid & 63) == 0) rsum[tid >> 6] = v;
    __syncthreads();
    if (tid == 0) atomicAdd(out, rsum[0] + rsum[1] + rsum[2] + rsum[3]);
  }
}

extern "C" void kernel_launch(void* const* d_in, const int* in_sizes, int n_in,
                              void* d_out, int out_size, void* d_ws, size_t ws_size,
                              hipStream_t stream) {
  const float* X   = (const float*)d_in[0];
  const float* Y   = (const float*)d_in[1];
  const float* R   = (const float*)d_in[2];
  const float* S   = (const float*)d_in[3];
  const float* t   = (const float*)d_in[4];
  const float* Rgt = (const float*)d_in[5];
  const float* Sgt = (const float*)d_in[6];
  const float* tgt = (const float*)d_in[7];

  float* partial = (float*)d_ws;
  float* out     = (float*)d_out;

  hipMemsetAsync(out, 0, sizeof(float), stream);

  dim3 gA(NN / PTS_PER_BLOCK, NCHUNK, 2 * BB);   // (2, 16, 16) = 512 blocks
  chamfer_partial<<<gA, TPB, 0, stream>>>(X, Y, partial);

  chamfer_reduce<<<NPTS / 1024, 256, 0, stream>>>(partial, R, S, t, Rgt, Sgt, tgt, out);
}